// Round 14
// baseline (52.040 us; speedup 1.0000x reference)
//
#include <hip/hip_runtime.h>
#include <hip/hip_bf16.h>

// EdgeConv: B=8, C=64, N=4096, K=16, O=64
// out[n] = relu(F[n] + max_k G[src[n,k]]);  F = x@(Wa-Wb)+bias, G = x@Wb.
//
// Physically-pinned two-dispatch design (R6/R12/R13 synthesis):
//  - Harness order is validate -> poison ws (fills every L2 with 0xAA lines) -> replay.
//    A consumer reading a line produced on ANOTHER XCD can hit fill-fresh poison
//    (R6). Same-physical-XCD produce->consume write-hits the poison away (R12
//    passed post-timing). So both kernels pin work by HW_REG_XCC_ID: XCD b owns
//    batch b. Tiles distributed by one-shot atomic tickets (no spin - R12's 77us
//    was the polling barrier; dispatch boundary is the proven-cheap barrier).
//  - Per-XCD gather working set = batch b's G = 512 KB -> L2-resident -> gathers
//    at L2 rate instead of the ~31 req/ns L3 ceiling that pinned R8-R13 at 24us.
//  - NO __threadfence / coop launch (R4/5/7/10 evidence).

#define BB 8
#define CC 64
#define NN 4096
#define KK 16
#define OO 64

typedef __bf16 bf16x8 __attribute__((ext_vector_type(8)));
typedef float f32x4 __attribute__((ext_vector_type(4)));

union Frag { int4 i; bf16x8 v; };
union PackA { bf16x8 v; __hip_bfloat16 h[8]; };

static constexpr size_t G_BYTES = (size_t)BB * NN * 64 * 2;   // 4 MB

// ---------------- k1: G = x@Wb for batch = own XCD, ticketed 64-node tiles ----------------
__global__ __launch_bounds__(256, 3) void g_gemm_xcd(
    const float* __restrict__ x, const float* __restrict__ W,
    __hip_bfloat16* __restrict__ G, unsigned* __restrict__ ctr) {
    __shared__ float xt[64][65];
    __shared__ int4 wfl[8][64];
    __shared__ unsigned s_t;

    int t = threadIdx.x, w = t >> 6, l = t & 63;
    unsigned xreg;
    asm volatile("s_getreg_b32 %0, hwreg(HW_REG_XCC_ID)" : "=s"(xreg));
    int b = (int)(xreg & 7);

    {   // Wb fragments (once per block)
        __hip_bfloat16* wlu = (__hip_bfloat16*)wfl;
        int o = t & 63, h = t >> 6;
        #pragma unroll
        for (int kk = 0; kk < 16; ++kk) {
            int k = h * 16 + kk;
            float wb = W[(64 + k) * OO + o];
            int gq = (k >> 3) & 3, j = k & 7, ks = k >> 5;
            int lane = (gq << 4) | (o & 15);
            int fs = ks * 4 + (o >> 4);
            wlu[((fs * 64 + lane) << 3) | j] = __float2bfloat16(wb);
        }
    }
    __syncthreads();
    Frag wf[2][4];
    #pragma unroll
    for (int ks = 0; ks < 2; ++ks)
        #pragma unroll
        for (int ot = 0; ot < 4; ++ot)
            wf[ks][ot].i = wfl[ks * 4 + ot][l];

    const float* xb = x + (size_t)b * CC * NN;
    int node = (w << 4) + (l & 15);

    for (;;) {
        if (t == 0) s_t = atomicAdd(&ctr[b], 1u);
        __syncthreads();                  // also separates prev tile's xt reads from next writes
        unsigned tt = s_t;
        if (tt >= 64u) break;
        int n0 = (int)tt << 6;

        #pragma unroll
        for (int it = 0; it < 4; ++it) {
            int idx = it * 256 + t, c = idx >> 4, q = idx & 15;
            float4 v = *(const float4*)(xb + (size_t)c * NN + n0 + q * 4);
            xt[c][q * 4 + 0] = v.x; xt[c][q * 4 + 1] = v.y;
            xt[c][q * 4 + 2] = v.z; xt[c][q * 4 + 3] = v.w;
        }
        __syncthreads();

        f32x4 acc[4];
        #pragma unroll
        for (int ot = 0; ot < 4; ++ot) acc[ot] = f32x4{0.f, 0.f, 0.f, 0.f};
        #pragma unroll
        for (int ks = 0; ks < 2; ++ks) {
            PackA a;
            #pragma unroll
            for (int j = 0; j < 8; ++j)
                a.h[j] = __float2bfloat16(xt[ks * 32 + ((l >> 4) << 3) + j][node]);
            #pragma unroll
            for (int ot = 0; ot < 4; ++ot)
                acc[ot] = __builtin_amdgcn_mfma_f32_16x16x32_bf16(a.v, wf[ks][ot].v, acc[ot], 0, 0, 0);
        }
        size_t base = ((size_t)b * NN + n0 + (w << 4)) * 64;
        #pragma unroll
        for (int ot = 0; ot < 4; ++ot)
            #pragma unroll
            for (int r = 0; r < 4; ++r) {
                int nd = ((l >> 4) << 2) + r;
                G[base + (size_t)nd * 64 + ot * 16 + (l & 15)] = __float2bfloat16(acc[ot][r]);
            }
    }
}

// ---------------- k2: F in-kernel + gather-max, batch = own XCD, ticketed 32-node tiles ----------------
__global__ __launch_bounds__(256, 4) void gather_max_xcd(
    const float* __restrict__ x, const int* __restrict__ ei,
    const float* __restrict__ W, const float* __restrict__ bias,
    const uint2* __restrict__ Gq, float* __restrict__ out,
    unsigned* __restrict__ ctr) {
    __shared__ union { float xt[64][33]; float ot_[64][33]; } sm;
    __shared__ int4 wfl[8][64];
    __shared__ float Fl[32][65];
    __shared__ unsigned s_t;

    int t = threadIdx.x, w = t >> 6, l = t & 63;
    unsigned xreg;
    asm volatile("s_getreg_b32 %0, hwreg(HW_REG_XCC_ID)" : "=s"(xreg));
    int b = (int)(xreg & 7);

    {   // (Wa-Wb) fragments (once per block)
        __hip_bfloat16* wlu = (__hip_bfloat16*)wfl;
        int o = t & 63, h = t >> 6;
        #pragma unroll
        for (int kk = 0; kk < 16; ++kk) {
            int k = h * 16 + kk;
            float v = W[k * OO + o] - W[(64 + k) * OO + o];
            int gq = (k >> 3) & 3, j = k & 7, ks = k >> 5;
            int lane = (gq << 4) | (o & 15);
            int fs = ks * 4 + (o >> 4);
            wlu[((fs * 64 + lane) << 3) | j] = __float2bfloat16(v);
        }
    }
    __syncthreads();

    int ng = (w & 1) << 4, ob = (w >> 1) << 1;   // F-phase wave roles
    Frag wfA[2][2];
    #pragma unroll
    for (int ks = 0; ks < 2; ++ks)
        #pragma unroll
        for (int oo = 0; oo < 2; ++oo)
            wfA[ks][oo].i = wfl[ks * 4 + ob + oo][l];
    float bv[2];
    #pragma unroll
    for (int oo = 0; oo < 2; ++oo) bv[oo] = bias[(ob + oo) * 16 + (l & 15)];

    const float* xb = x + (size_t)b * CC * NN;
    const int* srcp = ei + (size_t)b * NN * KK;
    size_t bbase = (size_t)b * NN;
    float* ob2 = out + (size_t)b * OO * NN;
    int eg = l >> 4, c = l & 15;

    for (;;) {
        if (t == 0) s_t = atomicAdd(&ctr[8 + b], 1u);
        __syncthreads();                  // separates prev tile's ot_ reads from next xt writes
        unsigned tt = s_t;
        if (tt >= 128u) break;
        int n0 = (int)tt << 5;
        int nb = n0 + (w << 3);

        #pragma unroll
        for (int it = 0; it < 8; ++it) {
            int idx = it * 256 + t, cc2 = idx >> 5, nn = idx & 31;
            sm.xt[cc2][nn] = xb[(size_t)cc2 * NN + n0 + nn];
        }
        int idxv[8];
        #pragma unroll
        for (int i = 0; i < 8; ++i) idxv[i] = srcp[(nb + i) * KK + c];
        __syncthreads();

        // F phase -> Fl
        {
            f32x4 acc[2];
            #pragma unroll
            for (int oo = 0; oo < 2; ++oo) acc[oo] = f32x4{bv[oo], bv[oo], bv[oo], bv[oo]};
            #pragma unroll
            for (int ks = 0; ks < 2; ++ks) {
                PackA a;
                #pragma unroll
                for (int j = 0; j < 8; ++j)
                    a.h[j] = __float2bfloat16(sm.xt[ks * 32 + ((l >> 4) << 3) + j][ng + (l & 15)]);
                #pragma unroll
                for (int oo = 0; oo < 2; ++oo)
                    acc[oo] = __builtin_amdgcn_mfma_f32_16x16x32_bf16(a.v, wfA[ks][oo].v, acc[oo], 0, 0, 0);
            }
            #pragma unroll
            for (int oo = 0; oo < 2; ++oo)
                #pragma unroll
                for (int r = 0; r < 4; ++r)
                    Fl[ng + ((l >> 4) << 2) + r][(ob + oo) * 16 + (l & 15)] = acc[oo][r];
        }
        __syncthreads();   // Fl ready; xt dead -> ot_ usable

        // G gathers (all 32 upfront), L2-local
        uint2 g[8][4];
        #pragma unroll
        for (int i = 0; i < 8; ++i)
            #pragma unroll
            for (int q = 0; q < 4; ++q) {
                int vk = __shfl(idxv[i], (q << 2) | eg);
                g[i][q] = Gq[(bbase + (size_t)vk) * 16 + c];
            }

        #pragma unroll
        for (int i = 0; i < 8; ++i) {
            float m0 = -3.4e38f, m1 = -3.4e38f, m2 = -3.4e38f, m3 = -3.4e38f;
            #pragma unroll
            for (int q = 0; q < 4; ++q) {
                m0 = fmaxf(m0, __uint_as_float(g[i][q].x << 16));
                m1 = fmaxf(m1, __uint_as_float(g[i][q].x & 0xffff0000u));
                m2 = fmaxf(m2, __uint_as_float(g[i][q].y << 16));
                m3 = fmaxf(m3, __uint_as_float(g[i][q].y & 0xffff0000u));
            }
            m0 = fmaxf(m0, __shfl_xor(m0, 16)); m0 = fmaxf(m0, __shfl_xor(m0, 32));
            m1 = fmaxf(m1, __shfl_xor(m1, 16)); m1 = fmaxf(m1, __shfl_xor(m1, 32));
            m2 = fmaxf(m2, __shfl_xor(m2, 16)); m2 = fmaxf(m2, __shfl_xor(m2, 32));
            m3 = fmaxf(m3, __shfl_xor(m3, 16)); m3 = fmaxf(m3, __shfl_xor(m3, 32));
            if (eg == (i & 3)) {
                int nl = (w << 3) + i;
                sm.ot_[4 * c + 0][nl] = fmaxf(Fl[nl][4 * c + 0] + m0, 0.0f);
                sm.ot_[4 * c + 1][nl] = fmaxf(Fl[nl][4 * c + 1] + m1, 0.0f);
                sm.ot_[4 * c + 2][nl] = fmaxf(Fl[nl][4 * c + 2] + m2, 0.0f);
                sm.ot_[4 * c + 3][nl] = fmaxf(Fl[nl][4 * c + 3] + m3, 0.0f);
            }
        }
        __syncthreads();

        #pragma unroll
        for (int it = 0; it < 8; ++it) {
            int idx = it * 256 + t, o = idx >> 5, nn = idx & 31;
            ob2[(size_t)o * NN + n0 + nn] = sm.ot_[o][nn];
        }
    }
}

extern "C" void kernel_launch(void* const* d_in, const int* in_sizes, int n_in,
                              void* d_out, int out_size, void* d_ws, size_t ws_size,
                              hipStream_t stream) {
    const float* x    = (const float*)d_in[0];   // [B,C,N,1] f32
    const int*   ei   = (const int*)d_in[1];     // [2,B,N,K] i32
    const float* W    = (const float*)d_in[2];   // [128,64] f32
    const float* bias = (const float*)d_in[3];   // [64] f32
    float* out = (float*)d_out;                  // [B,O,N,1] f32

    __hip_bfloat16* G = (__hip_bfloat16*)d_ws;                // 4 MB
    unsigned* ctr = (unsigned*)((char*)d_ws + G_BYTES);       // 64 B tickets

    hipMemsetAsync(ctr, 0, 128, stream);
    hipLaunchKernelGGL(g_gemm_xcd, dim3(512), dim3(256), 0, stream, x, W, G, ctr);
    hipLaunchKernelGGL(gather_max_xcd, dim3(1024), dim3(256), 0, stream,
                       x, ei, W, bias, (const uint2*)G, out, ctr);
}

// Round 15
// 39.558 us; speedup vs baseline: 1.3155x; 1.3155x over previous
//
#include <hip/hip_runtime.h>
#include <hip/hip_bf16.h>

// EdgeConv: B=8, C=64, N=4096, K=16, O=64
// out[n] = relu(F[n] + max_k G[src[n,k]]);  F = x@(Wa-Wb)+bias, G = x@Wb.
//
// R15 = R14 minus the hipMemsetAsync (tiny fill dispatch = ~40us/replay, the real
// R14 regression). k1: plain ticketless G-GEMM; block 0 zeroes k2's ticket
// counters (dispatch boundary publishes - proven across 6 passing rounds).
// k2: XCC-pinned (HW_REG_XCC_ID) ticketed gather - XCD b owns batch b, so the
// per-XCD gather set is 512 KB -> stays in the 4 MB L2 ACROSS REPLAYS (R6's
// 6.8us replay vs 20.4us cold = this warmth signature). R14 proved the pinned
// ticket structure passes post-timing (coherence-safe: same-XCD re-reads).
// NO __threadfence / coop / spin (R4/5/7/10/12 evidence).

#define BB 8
#define CC 64
#define NN 4096
#define KK 16
#define OO 64

typedef __bf16 bf16x8 __attribute__((ext_vector_type(8)));
typedef float f32x4 __attribute__((ext_vector_type(4)));

union Frag { int4 i; bf16x8 v; };
union PackA { bf16x8 v; __hip_bfloat16 h[8]; };

static constexpr size_t G_BYTES = (size_t)BB * NN * 64 * 2;   // 4 MB

// ---------------- k1: G = x@Wb -> [B*N][64] bf16 (plain mapping, ticketless) ----------------
__global__ __launch_bounds__(256, 3) void g_gemm(
    const float* __restrict__ x, const float* __restrict__ W,
    __hip_bfloat16* __restrict__ G, unsigned* __restrict__ ctr) {
    __shared__ float xt[64][65];
    __shared__ int4 wfl[8][64];

    int t = threadIdx.x, w = t >> 6, l = t & 63;
    if (blockIdx.x == 0 && t < 16) ctr[t] = 0;     // init k2 tickets (boundary publishes)
    int b = blockIdx.x >> 6;
    int n0 = (blockIdx.x & 63) << 6;

    const float* xb = x + (size_t)b * CC * NN;
    #pragma unroll
    for (int it = 0; it < 4; ++it) {
        int idx = it * 256 + t, c = idx >> 4, q = idx & 15;
        float4 v = *(const float4*)(xb + (size_t)c * NN + n0 + q * 4);
        xt[c][q * 4 + 0] = v.x; xt[c][q * 4 + 1] = v.y;
        xt[c][q * 4 + 2] = v.z; xt[c][q * 4 + 3] = v.w;
    }
    {   // Wb fragments
        __hip_bfloat16* wlu = (__hip_bfloat16*)wfl;
        int o = t & 63, h = t >> 6;
        #pragma unroll
        for (int kk = 0; kk < 16; ++kk) {
            int k = h * 16 + kk;
            float wb = W[(64 + k) * OO + o];
            int gq = (k >> 3) & 3, j = k & 7, ks = k >> 5;
            int lane = (gq << 4) | (o & 15);
            int fs = ks * 4 + (o >> 4);
            wlu[((fs * 64 + lane) << 3) | j] = __float2bfloat16(wb);
        }
    }
    __syncthreads();

    Frag wf[2][4];
    #pragma unroll
    for (int ks = 0; ks < 2; ++ks)
        #pragma unroll
        for (int ot = 0; ot < 4; ++ot)
            wf[ks][ot].i = wfl[ks * 4 + ot][l];

    f32x4 acc[4];
    #pragma unroll
    for (int ot = 0; ot < 4; ++ot) acc[ot] = f32x4{0.f, 0.f, 0.f, 0.f};

    int node = (w << 4) + (l & 15);
    #pragma unroll
    for (int ks = 0; ks < 2; ++ks) {
        PackA a;
        #pragma unroll
        for (int j = 0; j < 8; ++j)
            a.h[j] = __float2bfloat16(xt[ks * 32 + ((l >> 4) << 3) + j][node]);
        #pragma unroll
        for (int ot = 0; ot < 4; ++ot)
            acc[ot] = __builtin_amdgcn_mfma_f32_16x16x32_bf16(a.v, wf[ks][ot].v, acc[ot], 0, 0, 0);
    }

    size_t base = ((size_t)b * NN + n0 + (w << 4)) * 64;
    #pragma unroll
    for (int ot = 0; ot < 4; ++ot)
        #pragma unroll
        for (int r = 0; r < 4; ++r) {
            int nd = ((l >> 4) << 2) + r;
            G[base + (size_t)nd * 64 + ot * 16 + (l & 15)] = __float2bfloat16(acc[ot][r]);
        }
}

// ---------------- k2: F in-kernel + gather-max, XCC-pinned + ticketed ----------------
__global__ __launch_bounds__(256, 4) void gather_max_xcd(
    const float* __restrict__ x, const int* __restrict__ ei,
    const float* __restrict__ W, const float* __restrict__ bias,
    const uint2* __restrict__ Gq, float* __restrict__ out,
    unsigned* __restrict__ ctr) {
    __shared__ union { float xt[64][33]; float ot_[64][33]; } sm;
    __shared__ int4 wfl[8][64];
    __shared__ float Fl[32][65];
    __shared__ unsigned s_t;

    int t = threadIdx.x, w = t >> 6, l = t & 63;
    unsigned xreg;
    asm volatile("s_getreg_b32 %0, hwreg(HW_REG_XCC_ID)" : "=s"(xreg));
    int b = (int)(xreg & 7);

    {   // (Wa-Wb) fragments
        __hip_bfloat16* wlu = (__hip_bfloat16*)wfl;
        int o = t & 63, h = t >> 6;
        #pragma unroll
        for (int kk = 0; kk < 16; ++kk) {
            int k = h * 16 + kk;
            float v = W[k * OO + o] - W[(64 + k) * OO + o];
            int gq = (k >> 3) & 3, j = k & 7, ks = k >> 5;
            int lane = (gq << 4) | (o & 15);
            int fs = ks * 4 + (o >> 4);
            wlu[((fs * 64 + lane) << 3) | j] = __float2bfloat16(v);
        }
    }
    __syncthreads();

    int ng = (w & 1) << 4, ob = (w >> 1) << 1;   // F-phase wave roles
    Frag wfA[2][2];
    #pragma unroll
    for (int ks = 0; ks < 2; ++ks)
        #pragma unroll
        for (int oo = 0; oo < 2; ++oo)
            wfA[ks][oo].i = wfl[ks * 4 + ob + oo][l];
    float bv[2];
    #pragma unroll
    for (int oo = 0; oo < 2; ++oo) bv[oo] = bias[(ob + oo) * 16 + (l & 15)];

    const float* xb = x + (size_t)b * CC * NN;
    const int* srcp = ei + (size_t)b * NN * KK;
    size_t bbase = (size_t)b * NN;
    float* ob2 = out + (size_t)b * OO * NN;
    int eg = l >> 4, c = l & 15;

    for (;;) {
        if (t == 0) s_t = atomicAdd(&ctr[b], 1u);
        __syncthreads();
        unsigned tt = s_t;
        if (tt >= 128u) break;
        int n0 = (int)tt << 5;
        int nb = n0 + (w << 3);

        #pragma unroll
        for (int it = 0; it < 8; ++it) {
            int idx = it * 256 + t, cc2 = idx >> 5, nn = idx & 31;
            sm.xt[cc2][nn] = xb[(size_t)cc2 * NN + n0 + nn];
        }
        int idxv[8];
        #pragma unroll
        for (int i = 0; i < 8; ++i) idxv[i] = srcp[(nb + i) * KK + c];
        __syncthreads();

        // F phase -> Fl
        {
            f32x4 acc[2];
            #pragma unroll
            for (int oo = 0; oo < 2; ++oo) acc[oo] = f32x4{bv[oo], bv[oo], bv[oo], bv[oo]};
            #pragma unroll
            for (int ks = 0; ks < 2; ++ks) {
                PackA a;
                #pragma unroll
                for (int j = 0; j < 8; ++j)
                    a.h[j] = __float2bfloat16(sm.xt[ks * 32 + ((l >> 4) << 3) + j][ng + (l & 15)]);
                #pragma unroll
                for (int oo = 0; oo < 2; ++oo)
                    acc[oo] = __builtin_amdgcn_mfma_f32_16x16x32_bf16(a.v, wfA[ks][oo].v, acc[oo], 0, 0, 0);
            }
            #pragma unroll
            for (int oo = 0; oo < 2; ++oo)
                #pragma unroll
                for (int r = 0; r < 4; ++r)
                    Fl[ng + ((l >> 4) << 2) + r][(ob + oo) * 16 + (l & 15)] = acc[oo][r];
        }
        __syncthreads();   // Fl ready; xt dead -> ot_ usable

        // G gathers (32 upfront), served by warm local L2 across replays
        uint2 g[8][4];
        #pragma unroll
        for (int i = 0; i < 8; ++i)
            #pragma unroll
            for (int q = 0; q < 4; ++q) {
                int vk = __shfl(idxv[i], (q << 2) | eg);
                g[i][q] = Gq[(bbase + (size_t)vk) * 16 + c];
            }

        #pragma unroll
        for (int i = 0; i < 8; ++i) {
            float m0 = -3.4e38f, m1 = -3.4e38f, m2 = -3.4e38f, m3 = -3.4e38f;
            #pragma unroll
            for (int q = 0; q < 4; ++q) {
                m0 = fmaxf(m0, __uint_as_float(g[i][q].x << 16));
                m1 = fmaxf(m1, __uint_as_float(g[i][q].x & 0xffff0000u));
                m2 = fmaxf(m2, __uint_as_float(g[i][q].y << 16));
                m3 = fmaxf(m3, __uint_as_float(g[i][q].y & 0xffff0000u));
            }
            m0 = fmaxf(m0, __shfl_xor(m0, 16)); m0 = fmaxf(m0, __shfl_xor(m0, 32));
            m1 = fmaxf(m1, __shfl_xor(m1, 16)); m1 = fmaxf(m1, __shfl_xor(m1, 32));
            m2 = fmaxf(m2, __shfl_xor(m2, 16)); m2 = fmaxf(m2, __shfl_xor(m2, 32));
            m3 = fmaxf(m3, __shfl_xor(m3, 16)); m3 = fmaxf(m3, __shfl_xor(m3, 32));
            if (eg == (i & 3)) {
                int nl = (w << 3) + i;
                sm.ot_[4 * c + 0][nl] = fmaxf(Fl[nl][4 * c + 0] + m0, 0.0f);
                sm.ot_[4 * c + 1][nl] = fmaxf(Fl[nl][4 * c + 1] + m1, 0.0f);
                sm.ot_[4 * c + 2][nl] = fmaxf(Fl[nl][4 * c + 2] + m2, 0.0f);
                sm.ot_[4 * c + 3][nl] = fmaxf(Fl[nl][4 * c + 3] + m3, 0.0f);
            }
        }
        __syncthreads();

        #pragma unroll
        for (int it = 0; it < 8; ++it) {
            int idx = it * 256 + t, o = idx >> 5, nn = idx & 31;
            ob2[(size_t)o * NN + n0 + nn] = sm.ot_[o][nn];
        }
    }
}

extern "C" void kernel_launch(void* const* d_in, const int* in_sizes, int n_in,
                              void* d_out, int out_size, void* d_ws, size_t ws_size,
                              hipStream_t stream) {
    const float* x    = (const float*)d_in[0];   // [B,C,N,1] f32
    const int*   ei   = (const int*)d_in[1];     // [2,B,N,K] i32
    const float* W    = (const float*)d_in[2];   // [128,64] f32
    const float* bias = (const float*)d_in[3];   // [64] f32
    float* out = (float*)d_out;                  // [B,O,N,1] f32

    __hip_bfloat16* G = (__hip_bfloat16*)d_ws;                // 4 MB
    unsigned* ctr = (unsigned*)((char*)d_ws + G_BYTES);       // 64 B tickets

    hipLaunchKernelGGL(g_gemm, dim3(BB * (NN / 64)), dim3(256), 0, stream,
                       x, W, G, ctr);
    hipLaunchKernelGGL(gather_max_xcd, dim3(1024), dim3(256), 0, stream,
                       x, ei, W, bias, (const uint2*)G, out, ctr);
}

// Round 16
// 24.192 us; speedup vs baseline: 2.1511x; 1.6351x over previous
//
#include <hip/hip_runtime.h>
#include <hip/hip_bf16.h>

// EdgeConv: B=8, C=64, N=4096, K=16, O=64  — FINAL (roofline) version = R9, 24.0us.
// Key identity: out[n] = relu(F[n] + max_k G[src[n,k]]),
//   F = x@(Wa-Wb)+bias, G = x@Wb   (max commutes with lane-constant add; relu with max)
// k1: dense GEMM -> FG[B*N][128] bf16 (cols 0-63 = F, 64-127 = G)
// k2: per-node wave, half-wave ushort2 gathers (one instr = two full G rows).
//
// Roofline: the gather is 512K random 128B line requests, served at the measured
// ~31 lines/ns LLC ceiling (=~17us) in EVERY correct configuration (R8/R9/R11/R13
// all 24.0-24.6us; instruction count, MLP, XCD locality, traffic cuts all null).
// Config invariants (15 rounds of evidence): plain block mapping; no XCD swizzle
// (R6 stale-G divergence; R10/R14/R15 slower); no __threadfence (R7/R10: +40-60us);
// no coop/atomic barriers (R4/5/12: 3-5x); no tiny memset dispatches (R14: +40us).

#define BB 8
#define CC 64
#define NN 4096
#define KK 16
#define OO 64

typedef __bf16 bf16x8 __attribute__((ext_vector_type(8)));
typedef float f32x4 __attribute__((ext_vector_type(4)));

union Frag { int4 i; bf16x8 v; };
union PackA { bf16x8 v; __hip_bfloat16 h[8]; };

// ---------------- k1: FG = [x@(Wa-Wb)+bias | x@Wb] ----------------
// Block: 64 nodes of one batch. M=64, N2=128, K=64. 4 waves, 16 MFMA each.
__global__ __launch_bounds__(256, 3) void fg_gemm(
    const float* __restrict__ x, const float* __restrict__ W,
    const float* __restrict__ bias, __hip_bfloat16* __restrict__ FG) {
    __shared__ float xt[64][65];      // [c][node] f32, +1 pad
    __shared__ int4 wfl[16][64];      // B-frags: [ks*8+ot][lane]

    int t = threadIdx.x, w = t >> 6, l = t & 63;
    int b = blockIdx.x >> 6;          // plain mapping
    int n0 = (blockIdx.x & 63) << 6;

    // load x tile (float4, coalesced along n)
    const float* xb = x + (size_t)b * CC * NN;
    #pragma unroll
    for (int it = 0; it < 4; ++it) {
        int idx = it * 256 + t;       // 1024 float4 = 64 rows x 16
        int c = idx >> 4, q = idx & 15;
        float4 v = *(const float4*)(xb + (size_t)c * NN + n0 + q * 4);
        xt[c][q * 4 + 0] = v.x; xt[c][q * 4 + 1] = v.y;
        xt[c][q * 4 + 2] = v.z; xt[c][q * 4 + 3] = v.w;
    }
    // build Wcmb B-fragments: Wcmb[k][o2] = (o2<64 ? Wa-Wb : Wb)[k][o2&63]
    {
        __hip_bfloat16* wlu = (__hip_bfloat16*)wfl;
        int o = t & 63, h = t >> 6;
        #pragma unroll
        for (int kk = 0; kk < 16; ++kk) {
            int k = h * 16 + kk;
            float wa = W[k * OO + o];          // coalesced (o consecutive)
            float wb = W[(64 + k) * OO + o];
            int g = (k >> 3) & 3, j = k & 7, ks = k >> 5;
            int lane = (g << 4) | (o & 15);
            int fsA = ks * 8 + (o >> 4);       // o2 = o      (F part)
            int fsB = fsA + 4;                 // o2 = 64 + o (G part)
            wlu[((fsA * 64 + lane) << 3) | j] = __float2bfloat16(wa - wb);
            wlu[((fsB * 64 + lane) << 3) | j] = __float2bfloat16(wb);
        }
    }
    __syncthreads();

    Frag wf[2][8];
    #pragma unroll
    for (int ks = 0; ks < 2; ++ks)
        #pragma unroll
        for (int ot = 0; ot < 8; ++ot)
            wf[ks][ot].i = wfl[ks * 8 + ot][l];

    f32x4 acc[8];
    #pragma unroll
    for (int ot = 0; ot < 8; ++ot) {
        float bv = (ot < 4) ? bias[ot * 16 + (l & 15)] : 0.0f;
        acc[ot] = f32x4{bv, bv, bv, bv};
    }

    int node = (w << 4) + (l & 15);   // A row = lane&15
    #pragma unroll
    for (int ks = 0; ks < 2; ++ks) {
        PackA a;
        #pragma unroll
        for (int j = 0; j < 8; ++j)
            a.h[j] = __float2bfloat16(xt[ks * 32 + ((l >> 4) << 3) + j][node]);
        #pragma unroll
        for (int ot = 0; ot < 8; ++ot)
            acc[ot] = __builtin_amdgcn_mfma_f32_16x16x32_bf16(a.v, wf[ks][ot].v, acc[ot], 0, 0, 0);
    }

    // D: col = lane&15, row = (lane>>4)*4 + r  (m89-verified layout)
    size_t base = ((size_t)b * NN + n0 + (w << 4)) * 128;
    #pragma unroll
    for (int ot = 0; ot < 8; ++ot)
        #pragma unroll
        for (int r = 0; r < 4; ++r) {
            int nd = ((l >> 4) << 2) + r;
            FG[base + (size_t)nd * 128 + ot * 16 + (l & 15)] = __float2bfloat16(acc[ot][r]);
        }
}

// ---------------- k2: out[b][o][n] = relu(F[n][o] + max_k G[src[n][k]][o]) ----------------
// Half-wave gather: lanes 0-31 = even edges, 32-63 = odd edges; each lane loads
// ushort2 (2 channels). One instr fetches TWO full 128B G rows. Parities combine
// via shfl_xor(32). bf16->f32 is free bit-masking on the packed uint.
__global__ __launch_bounds__(256, 4) void gather_max(
    const int* __restrict__ ei, const unsigned int* __restrict__ FG2,
    float* __restrict__ out) {
    __shared__ float otile[64][33];   // [o][node_local]
    int t = threadIdx.x, w = t >> 6, l = t & 63;
    int b = blockIdx.x >> 7;          // plain mapping
    int n0 = (blockIdx.x & 127) << 5;

    const int* srcp = ei + (size_t)b * NN * KK;   // ei[0][b]
    size_t bbase = (size_t)b * NN;
    int nb = n0 + (w << 3);
    int h = l >> 5;                   // edge parity handled by this half-wave
    int cp = l & 31;                  // channel-pair index (channels 2cp, 2cp+1)

    int idxv[8];
    #pragma unroll
    for (int i = 0; i < 8; ++i) idxv[i] = srcp[(nb + i) * KK + (l & 15)];

    unsigned int fv[8];               // F channels (2cp,2cp+1), rows = own nodes
    #pragma unroll
    for (int i = 0; i < 8; ++i) fv[i] = FG2[((bbase + nb + i) << 6) + cp];

    #pragma unroll
    for (int i = 0; i < 8; ++i) {
        unsigned int g[8];
        #pragma unroll
        for (int j = 0; j < 8; ++j) {
            int vk = __shfl(idxv[i], (j << 1) | h);   // edge 2j+h's src node
            g[j] = FG2[(((size_t)bbase + vk) << 6) + 32 + cp];
        }
        float m0 = -3.4e38f, m1 = -3.4e38f;
        #pragma unroll
        for (int j = 0; j < 8; ++j) {
            m0 = fmaxf(m0, __uint_as_float(g[j] << 16));          // low bf16
            m1 = fmaxf(m1, __uint_as_float(g[j] & 0xffff0000u));  // high bf16
        }
        m0 = fmaxf(m0, __shfl_xor(m0, 32));   // combine edge parities
        m1 = fmaxf(m1, __shfl_xor(m1, 32));
        if (!h) {
            int nl = (w << 3) + i;
            otile[2 * cp + 0][nl] = fmaxf(__uint_as_float(fv[i] << 16) + m0, 0.0f);
            otile[2 * cp + 1][nl] = fmaxf(__uint_as_float(fv[i] & 0xffff0000u) + m1, 0.0f);
        }
    }
    __syncthreads();

    float* ob = out + (size_t)b * OO * NN;
    #pragma unroll
    for (int it = 0; it < 8; ++it) {
        int idx = it * 256 + t, o = idx >> 5, nn = idx & 31;
        ob[(size_t)o * NN + n0 + nn] = otile[o][nn];            // coalesced 128B rows
    }
}

extern "C" void kernel_launch(void* const* d_in, const int* in_sizes, int n_in,
                              void* d_out, int out_size, void* d_ws, size_t ws_size,
                              hipStream_t stream) {
    const float* x    = (const float*)d_in[0];   // [B,C,N,1] f32
    const int*   ei   = (const int*)d_in[1];     // [2,B,N,K] i32
    const float* W    = (const float*)d_in[2];   // [128,64] f32
    const float* bias = (const float*)d_in[3];   // [64] f32
    float* out = (float*)d_out;                  // [B,O,N,1] f32

    __hip_bfloat16* FG = (__hip_bfloat16*)d_ws;  // [B*N][128] bf16 = 8 MB

    hipLaunchKernelGGL(fg_gemm, dim3(BB * (NN / 64)), dim3(256), 0, stream,
                       x, W, bias, FG);
    hipLaunchKernelGGL(gather_max, dim3(BB * (NN / 32)), dim3(256), 0, stream,
                       ei, (const unsigned int*)FG, out);
}